// Round 19
// baseline (445.840 us; speedup 1.0000x reference)
//
#include <hip/hip_runtime.h>
#include <math.h>

// ---------------------------------------------------------------------------
// QoRNet: 3-layer GAT + pool + MLP head, fp32 (bf16 messages, MFMA GEMM).
// Edge GEMMs collapsed to E x 16 x 12 (only a_edge = <el,att_edge> is used).
// CSR (counting sort by dst) -> one wave per node, single-pass aggregation.
// R2-R17: see journal. Highlights: max-free softmax (R5), bf16 messages (R5),
// MFMA GEMM w/ split-precision weights (R6/7), gather-based CSR build (R4/13),
// boundary-based pool (R16), deg spread (R17: line-contention was rank's cost).
// R18: node_kernel inner loop manually unrolled x2 -> 16 gather chains in
//      flight per wave (was 8; dynamic trip count blocked compiler unroll;
//      VALU 51% = half stall on the src_csr->xlb dependent chain).
// ---------------------------------------------------------------------------

typedef __attribute__((ext_vector_type(8))) __bf16 bf16x8;
typedef __attribute__((ext_vector_type(4))) float f32x4;

union FragU {
  uint4 u;
  bf16x8 v;
};

union XU {
  uint4 u[2];
  __bf16 b[16];
};

__device__ __forceinline__ float lrelu(float x) { return x >= 0.f ? x : 0.2f * x; }

__device__ __forceinline__ unsigned pack_bf2(float a, float b) {
  unsigned ua = __float_as_uint(a), ub = __float_as_uint(b);
  ua += 0x7fffu + ((ua >> 16) & 1u);   // RNE
  ub += 0x7fffu + ((ub >> 16) & 1u);
  return (ua >> 16) | (ub & 0xffff0000u);
}
__device__ __forceinline__ unsigned short bf_of(float a) {
  unsigned ua = __float_as_uint(a);
  ua += 0x7fffu + ((ua >> 16) & 1u);
  return (unsigned short)(ua >> 16);
}
__device__ __forceinline__ float bf_lo(unsigned u) { return __uint_as_float(u << 16); }
__device__ __forceinline__ float bf_hi(unsigned u) { return __uint_as_float(u & 0xffff0000u); }

// ---------- CSR build ----------
// deg spread: deg[node*16] -> one 64B L2 line per node (atomic contention fix)
__global__ void rank_kernel(const int* __restrict__ dst, int* __restrict__ deg,
                            int* __restrict__ rank, int E) {
  int e = blockIdx.x * 256 + threadIdx.x;
  if (e < E) rank[e] = atomicAdd(&deg[(size_t)dst[e] * 16], 1);
}

// Phase A: per-block inclusive scan (strided deg) + block total + gb boundaries
__global__ __launch_bounds__(1024) void scanA_kernel(const int* __restrict__ deg,
                                                     const int* __restrict__ batch,
                                                     int* __restrict__ tmp,
                                                     int* __restrict__ bsum,
                                                     int* __restrict__ gb, int n) {
  __shared__ int wsum[16];
  int tid = threadIdx.x;
  int lane = tid & 63, wid = tid >> 6;
  int i = blockIdx.x * 1024 + tid;
  // group boundaries of sorted batch (fused gb_kernel)
  if (i == 0) gb[8] = n;
  if (i < n) {
    int b = batch[i];
    if (i == 0 || batch[i - 1] != b) gb[b] = i;
  }
  int v = (i < n) ? deg[(size_t)i * 16] : 0;
  int sv = v;
#pragma unroll
  for (int off = 1; off < 64; off <<= 1) {
    int t = __shfl_up(sv, off);
    if (lane >= off) sv += t;
  }
  if (lane == 63) wsum[wid] = sv;
  __syncthreads();
  if (wid == 0) {
    int wv = (lane < 16) ? wsum[lane] : 0;
#pragma unroll
    for (int off = 1; off < 16; off <<= 1) {
      int t = __shfl_up(wv, off);
      if (lane >= off) wv += t;
    }
    if (lane < 16) wsum[lane] = wv;
  }
  __syncthreads();
  int waveoff = (wid > 0) ? wsum[wid - 1] : 0;
  int incl = waveoff + sv;
  if (i < n) tmp[i] = incl;
  if (tid == 1023) bsum[blockIdx.x] = incl;
}

// Phase C (scanB fused): each block scans the <=64 block sums itself.
__global__ __launch_bounds__(1024) void scanC_kernel(const int* __restrict__ deg,
                                                     const int* __restrict__ tmp,
                                                     const int* __restrict__ bsum, int nb,
                                                     int* __restrict__ row_ptr, int n) {
  __shared__ int soff[2];
  int tid = threadIdx.x;
  if (tid < 64) {
    int v = (tid < nb) ? bsum[tid] : 0;
    int sv = v;
#pragma unroll
    for (int off = 1; off < 64; off <<= 1) {
      int t = __shfl_up(sv, off);
      if (tid >= off) sv += t;
    }
    if (tid == blockIdx.x) soff[0] = sv - v;  // exclusive offset for this block
    if (tid == 63) soff[1] = sv;              // grand total
  }
  __syncthreads();
  int i = blockIdx.x * 1024 + tid;
  if (i < n) row_ptr[i] = tmp[i] - deg[(size_t)i * 16] + soff[0];
  if (blockIdx.x == 0 && tid == 0) row_ptr[n] = soff[1];
}

// perm[pos] = e and src_csr[pos] = srcA[e]
__global__ void perm_kernel(const int* __restrict__ dst, const int* __restrict__ srcA,
                            const int* __restrict__ rank, const int* __restrict__ row_ptr,
                            int* __restrict__ perm, int* __restrict__ src_csr, int E) {
  int e = blockIdx.x * 256 + threadIdx.x;
  if (e < E) {
    int pos = row_ptr[dst[e]] + rank[e];
    perm[pos] = e;
    src_csr[pos] = srcA[e];
  }
}

// ---------- fused parameter prep: blocks 0-23 = weight split+transpose,
// block 24 = edge matrix M[16][12]+cvec ----------
__global__ __launch_bounds__(256) void prep_wp_kernel(const float* __restrict__ lin_w,
                                                      unsigned short* __restrict__ wt_hi,
                                                      unsigned short* __restrict__ wt_lo,
                                                      const float* __restrict__ lin_edge_w,
                                                      const float* __restrict__ att_edge,
                                                      const float* __restrict__ W_edge,
                                                      const float* __restrict__ b_edge,
                                                      float* __restrict__ Mc) {
  __shared__ float shmem[128 * 18];
  int t = threadIdx.x;
  if (blockIdx.x < 24) {
    float(*tile)[18] = (float(*)[18])shmem;
    int l = blockIdx.x >> 3;
    int n0 = (blockIdx.x & 7) * 16;
    const float* W = lin_w + (size_t)l * 16384;
    unsigned short* hi = wt_hi + (size_t)l * 16384;
    unsigned short* lo = wt_lo + (size_t)l * 16384;
    for (int idx = t; idx < 2048; idx += 256) {
      int k = idx >> 4, j = idx & 15;
      tile[k][j] = W[k * 128 + n0 + j];
    }
    __syncthreads();
    int r = t >> 4;
    int k0 = (t & 15) * 8;
    unsigned short hbuf[8], lbuf[8];
#pragma unroll
    for (int u = 0; u < 8; ++u) {
      float w = tile[k0 + u][r];
      unsigned short hb = bf_of(w);
      float hf = __uint_as_float((unsigned)hb << 16);
      hbuf[u] = hb;
      lbuf[u] = bf_of(w - hf);
    }
    size_t base = (size_t)(n0 + r) * 128 + k0;
    *(uint4*)(hi + base) = *(uint4*)hbuf;
    *(uint4*)(lo + base) = *(uint4*)lbuf;
  } else {
    float(*WE)[12] = (float(*)[12])shmem;
    for (int idx = t; idx < 128 * 12; idx += 256) {
      int k = idx / 12, j = idx - k * 12;
      int l = j >> 2, h = j & 3;
      float s = 0.f;
      for (int c = 0; c < 32; ++c)
        s += lin_edge_w[((size_t)l * 128 + k) * 128 + h * 32 + c] * att_edge[(l * 4 + h) * 32 + c];
      WE[k][j] = s;
    }
    __syncthreads();
    for (int idx = t; idx < 16 * 12; idx += 256) {
      int i = idx / 12, j = idx - i * 12;
      float s = 0.f;
      for (int k = 0; k < 128; ++k) s += W_edge[i * 128 + k] * WE[k][j];
      Mc[idx] = s;
    }
    if (t < 12) {
      float s = 0.f;
      for (int k = 0; k < 128; ++k) s += b_edge[k] * WE[k][t];
      Mc[192 + t] = s;
    }
  }
}

// ---------- CSR-ordered edge build: gather edge_attr, write bf16 planes ----------
__global__ void edge_build_kernel(const int* __restrict__ perm,
                                  const float* __restrict__ edge_attr,
                                  const float* __restrict__ Mc,
                                  unsigned short* __restrict__ a_edge_csr,  // [L][E][4] bf16
                                  int E) {
  __shared__ float M[16][12];
  __shared__ float cv[12];
  int t = threadIdx.x;
  if (t < 192) M[t / 12][t % 12] = Mc[t];
  if (t < 12) cv[t] = Mc[192 + t];
  __syncthreads();
  int i = blockIdx.x * 256 + t;
  if (i >= E) return;
  int e = perm[i];
  const float4* p = (const float4*)(edge_attr + (size_t)e * 16);  // one 64B line
  float4 v0 = p[0], v1 = p[1], v2 = p[2], v3 = p[3];
  float ea[16] = {v0.x, v0.y, v0.z, v0.w, v1.x, v1.y, v1.z, v1.w,
                  v2.x, v2.y, v2.z, v2.w, v3.x, v3.y, v3.z, v3.w};
  float a[12];
#pragma unroll
  for (int j = 0; j < 12; ++j) {
    float s = cv[j];
#pragma unroll
    for (int k = 0; k < 16; ++k) s += ea[k] * M[k][j];
    a[j] = s;
  }
#pragma unroll
  for (int l = 0; l < 3; ++l) {
    uint2 o;
    o.x = pack_bf2(a[l * 4 + 0], a[l * 4 + 1]);  // lo=h0, hi=h1
    o.y = pack_bf2(a[l * 4 + 2], a[l * 4 + 3]);  // lo=h2, hi=h3
    *(uint2*)(a_edge_csr + ((size_t)l * E + i) * 4) = o;
  }
}

// ---------- input projection: h = relu([x, recipe[batch]] @ W_in + b_in) ----------
__global__ __launch_bounds__(256) void proj_kernel(const float* __restrict__ x,
                                                   const float* __restrict__ recipe,
                                                   const int* __restrict__ batch,
                                                   const float* __restrict__ W_in,
                                                   const float* __restrict__ b_in,
                                                   float* __restrict__ h, int N) {
  __shared__ float Wc[72][128];
  __shared__ float Ac[64][72];
  int t = threadIdx.x;
  int tx = t & 31, ty = t >> 5;
  int row0 = blockIdx.x * 64;
  for (int idx = t; idx < 2304; idx += 256) {
    int k = idx >> 5, c4 = idx & 31;
    *(float4*)&Wc[k][c4 * 4] = *(const float4*)(W_in + (size_t)k * 128 + c4 * 4);
  }
  for (int idx = t; idx < 1024; idx += 256) {
    int r = idx >> 4, c4 = idx & 15;
    int row = row0 + r;
    float4 v = make_float4(0.f, 0.f, 0.f, 0.f);
    if (row < N) v = *(const float4*)(x + (size_t)row * 64 + c4 * 4);
    *(float4*)&Ac[r][c4 * 4] = v;
  }
  for (int idx = t; idx < 128; idx += 256) {
    int r = idx >> 1, c4 = idx & 1;
    int row = row0 + r;
    float4 v = make_float4(0.f, 0.f, 0.f, 0.f);
    if (row < N) v = *(const float4*)(recipe + (size_t)batch[row] * 8 + c4 * 4);
    *(float4*)&Ac[r][64 + c4 * 4] = v;
  }
  __syncthreads();
  float4 bias = *(const float4*)(b_in + tx * 4);
  float4 acc[8];
#pragma unroll
  for (int s = 0; s < 8; ++s) acc[s] = bias;
  for (int k4 = 0; k4 < 18; ++k4) {
    float4 w0 = *(float4*)&Wc[k4 * 4 + 0][tx * 4];
    float4 w1 = *(float4*)&Wc[k4 * 4 + 1][tx * 4];
    float4 w2 = *(float4*)&Wc[k4 * 4 + 2][tx * 4];
    float4 w3 = *(float4*)&Wc[k4 * 4 + 3][tx * 4];
#pragma unroll
    for (int s = 0; s < 8; ++s) {
      float4 av = *(float4*)&Ac[ty + 8 * s][k4 * 4];
      acc[s].x += av.x * w0.x + av.y * w1.x + av.z * w2.x + av.w * w3.x;
      acc[s].y += av.x * w0.y + av.y * w1.y + av.z * w2.y + av.w * w3.y;
      acc[s].z += av.x * w0.z + av.y * w1.z + av.z * w2.z + av.w * w3.z;
      acc[s].w += av.x * w0.w + av.y * w1.w + av.z * w2.w + av.w * w3.w;
    }
  }
#pragma unroll
  for (int s = 0; s < 8; ++s) {
    int row = row0 + ty + 8 * s;
    if (row < N) {
      float4 o = acc[s];
      o.x = fmaxf(o.x, 0.f); o.y = fmaxf(o.y, 0.f);
      o.z = fmaxf(o.z, 0.f); o.w = fmaxf(o.w, 0.f);
      *(float4*)(h + (size_t)row * 128 + tx * 4) = o;
    }
  }
}

// ---------- xl(bf16) = h @ (W_hi + W_lo) via MFMA + a_src/a_dst epilogue ----
__global__ __launch_bounds__(256) void gemm_mfma_kernel(
    const float* __restrict__ A, const unsigned short* __restrict__ wt_hi,
    const unsigned short* __restrict__ wt_lo,
    const float* __restrict__ att_s, const float* __restrict__ att_d,
    unsigned short* __restrict__ Cb, float* __restrict__ a_src,
    float* __restrict__ a_dst, int M) {
  int t = threadIdx.x;
  int lane = t & 63, w = t >> 6;
  int c = lane & 15, q = lane >> 4;
  int m0 = blockIdx.x * 64 + w * 16;
  int rowA = m0 + c;
  bool rowok = rowA < M;

  f32x4 acc[8];
#pragma unroll
  for (int n = 0; n < 8; ++n) acc[n] = 0.f;

#pragma unroll
  for (int kk = 0; kk < 128; kk += 32) {
    float4 fa0 = make_float4(0.f, 0.f, 0.f, 0.f), fa1 = fa0;
    if (rowok) {
      const float* ap = A + (size_t)rowA * 128 + kk + 8 * q;
      fa0 = *(const float4*)ap;
      fa1 = *(const float4*)(ap + 4);
    }
    FragU af;
    af.u.x = pack_bf2(fa0.x, fa0.y);
    af.u.y = pack_bf2(fa0.z, fa0.w);
    af.u.z = pack_bf2(fa1.x, fa1.y);
    af.u.w = pack_bf2(fa1.z, fa1.w);
    const unsigned short* bhp = wt_hi + (size_t)c * 128 + kk + 8 * q;
    const unsigned short* blp = wt_lo + (size_t)c * 128 + kk + 8 * q;
#pragma unroll
    for (int n = 0; n < 8; ++n) {
      FragU bh, bl;
      bh.u = *(const uint4*)(bhp + n * 2048);  // (n*16)*128 shorts
      bl.u = *(const uint4*)(blp + n * 2048);
      acc[n] = __builtin_amdgcn_mfma_f32_16x16x32_bf16(af.v, bh.v, acc[n], 0, 0, 0);
      acc[n] = __builtin_amdgcn_mfma_f32_16x16x32_bf16(af.v, bl.v, acc[n], 0, 0, 0);
    }
  }

  // epilogue: xl bf16 stores + a_src/a_dst reductions
  float asr[4][2], adr[4][2];
#pragma unroll
  for (int hh = 0; hh < 4; ++hh) {
    asr[hh][0] = att_s[32 * hh + c];
    asr[hh][1] = att_s[32 * hh + 16 + c];
    adr[hh][0] = att_d[32 * hh + c];
    adr[hh][1] = att_d[32 * hh + 16 + c];
  }
#pragma unroll
  for (int i = 0; i < 4; ++i) {
    int row = m0 + 4 * q + i;
    bool ok = row < M;
    if (ok) {
      size_t base = (size_t)row * 128;
#pragma unroll
      for (int n = 0; n < 8; ++n) Cb[base + n * 16 + c] = bf_of(acc[n][i]);
    }
#pragma unroll
    for (int hh = 0; hh < 4; ++hh) {
      float ps = acc[2 * hh][i] * asr[hh][0] + acc[2 * hh + 1][i] * asr[hh][1];
      float pd = acc[2 * hh][i] * adr[hh][0] + acc[2 * hh + 1][i] * adr[hh][1];
#pragma unroll
      for (int off = 1; off < 16; off <<= 1) {
        ps += __shfl_xor(ps, off);
        pd += __shfl_xor(pd, off);
      }
      if (ok && c == hh) {
        a_src[(size_t)row * 4 + hh] = ps;
        a_dst[(size_t)row * 4 + hh] = pd;
      }
    }
  }
}

// ---------- fused per-node max-free softmax aggregation (wave per node) ----------
// Inner loop unrolled x2: 16 gather chains in flight per wave.
__global__ __launch_bounds__(256) void node_kernel(const int* __restrict__ row_ptr,
                                                   const int* __restrict__ src_csr,
                                                   const float* __restrict__ a_src,
                                                   const float* __restrict__ a_dst,
                                                   const unsigned short* __restrict__ aep,  // [E][4] bf16 plane
                                                   const unsigned short* __restrict__ xlb,
                                                   const float* __restrict__ bias,
                                                   float* __restrict__ h_out, int N) {
  int lane = threadIdx.x & 63;
  int g = lane >> 3;        // edge group 0..7
  int t = lane & 7;         // channel lane, 16 ch each
  int h = t >> 1;           // head 0..3
  int n = blockIdx.x * 4 + (threadIdx.x >> 6);
  if (n >= N) return;
  int s = row_ptr[n], e = row_ptr[n + 1];

  const float* bp = bias + t * 16;
  float* op = h_out + (size_t)n * 128 + t * 16;
  if (e <= s) {
    if (g == 0) {
#pragma unroll
      for (int q = 0; q < 4; ++q) {
        float4 b = *(const float4*)(bp + q * 4);
        float4 o = make_float4(fmaxf(b.x, 0.f), fmaxf(b.y, 0.f), fmaxf(b.z, 0.f), fmaxf(b.w, 0.f));
        *(float4*)(op + q * 4) = o;
      }
    }
    return;
  }

  float ad = a_dst[(size_t)n * 4 + h];  // wave-uniform per head
  const unsigned* aepu = (const unsigned*)aep;
  int hw = h >> 1;   // which 32-bit word of the 8B entry
  int hb = h & 1;    // lo/hi half

  float den = 0.f;
  float num[16];
#pragma unroll
  for (int c = 0; c < 16; ++c) num[c] = 0.f;

  int i = s + g;
  // pairs (i, i+8): both dependent chains issued before either compute
  for (; i + 8 < e; i += 16) {
    int sc0 = src_csr[i];
    int sc1 = src_csr[i + 8];
    float as0 = a_src[(size_t)sc0 * 4 + h];
    float as1 = a_src[(size_t)sc1 * 4 + h];
    unsigned uae0 = aepu[(size_t)i * 2 + hw];
    unsigned uae1 = aepu[(size_t)(i + 8) * 2 + hw];
    const uint4* xp0 = (const uint4*)(xlb + (size_t)sc0 * 128 + t * 16);
    const uint4* xp1 = (const uint4*)(xlb + (size_t)sc1 * 128 + t * 16);
    XU xu0, xu1;
    xu0.u[0] = xp0[0]; xu0.u[1] = xp0[1];
    xu1.u[0] = xp1[0]; xu1.u[1] = xp1[1];
    float ae0 = hb ? bf_hi(uae0) : bf_lo(uae0);
    float ae1 = hb ? bf_hi(uae1) : bf_lo(uae1);
    float a0 = lrelu(as0 + ad + ae0);
    float a1 = lrelu(as1 + ad + ae1);
    float w0 = __expf(fminf(a0, 80.f));
    float w1 = __expf(fminf(a1, 80.f));
    den += w0 + w1;
#pragma unroll
    for (int c = 0; c < 16; ++c)
      num[c] += w0 * (float)xu0.b[c] + w1 * (float)xu1.b[c];
  }
  if (i < e) {
    int sc = src_csr[i];
    float as = a_src[(size_t)sc * 4 + h];
    unsigned uae = aepu[(size_t)i * 2 + hw];
    const uint4* xp = (const uint4*)(xlb + (size_t)sc * 128 + t * 16);
    XU xu;
    xu.u[0] = xp[0]; xu.u[1] = xp[1];
    float ae = hb ? bf_hi(uae) : bf_lo(uae);
    float a = lrelu(as + ad + ae);
    float w = __expf(fminf(a, 80.f));
    den += w;
#pragma unroll
    for (int c = 0; c < 16; ++c) num[c] += w * (float)xu.b[c];
  }

#pragma unroll
  for (int off = 8; off < 64; off <<= 1) {
    den += __shfl_xor(den, off);
#pragma unroll
    for (int c = 0; c < 16; ++c) num[c] += __shfl_xor(num[c], off);
  }

  if (g == 0) {
    float rh = 1.f / den;
#pragma unroll
    for (int q = 0; q < 4; ++q) {
      float4 b = *(const float4*)(bp + q * 4);
      float4 o;
      o.x = fmaxf(num[q * 4 + 0] * rh + b.x, 0.f);
      o.y = fmaxf(num[q * 4 + 1] * rh + b.y, 0.f);
      o.z = fmaxf(num[q * 4 + 2] * rh + b.z, 0.f);
      o.w = fmaxf(num[q * 4 + 3] * rh + b.w, 0.f);
      *(float4*)(op + q * 4) = o;
    }
  }
}

// ---------- pooling (mean): 8 groups x 32 chunks, branch-free, LDS reduce ----
__global__ __launch_bounds__(256) void pool_kernel(const float* __restrict__ h,
                                                   const int* __restrict__ gb,
                                                   float* __restrict__ g_sum, int N) {
  __shared__ int st[9];
  __shared__ float red[8][132];
  int t = threadIdx.x;
  if (t < 9) {
    int m = 0x7fffffff;
    for (int j = t; j < 9; ++j) m = min(m, gb[j]);   // gb[8] = N; unset groups huge
    st[t] = min(m, N);
  }
  __syncthreads();
  int g = blockIdx.x >> 5;       // group 0..7
  int chunk = blockIdx.x & 31;   // chunk 0..31
  int gs = st[g], ge = st[g + 1];
  int rows = ge - gs;
  int c4 = t & 31, sub = t >> 5; // 8 row-subs x 32 float4-lanes
  float ax = 0.f, ay = 0.f, az = 0.f, aw = 0.f;
  if (rows > 0) {
    int clen = (rows + 31) >> 5;
    int cs = gs + chunk * clen;
    int ce = min(cs + clen, ge);
    for (int r = cs + sub; r < ce; r += 8) {
      float4 v = *(const float4*)(h + (size_t)r * 128 + c4 * 4);
      ax += v.x; ay += v.y; az += v.z; aw += v.w;
    }
  }
  red[sub][c4 * 4 + 0] = ax;
  red[sub][c4 * 4 + 1] = ay;
  red[sub][c4 * 4 + 2] = az;
  red[sub][c4 * 4 + 3] = aw;
  __syncthreads();
  if (t < 128 && rows > 0) {
    float s = 0.f;
#pragma unroll
    for (int u = 0; u < 8; ++u) s += red[u][t];
    atomicAdd(&g_sum[(size_t)g * 128 + t], s);
  }
}

// ---------- head: relu(g@W1+b1)@W2+b2 ; counts from gb ----------
__global__ void head_kernel(const float* __restrict__ g_sum, const int* __restrict__ gb,
                            const float* __restrict__ W1, const float* __restrict__ b1,
                            const float* __restrict__ W2, const float* __restrict__ b2,
                            float* __restrict__ out, int N) {
  __shared__ float g[8][128];
  __shared__ float t1[8][128];
  __shared__ int st[9];
  int t = threadIdx.x;  // 256
  if (t < 9) {
    int m = 0x7fffffff;
    for (int j = t; j < 9; ++j) m = min(m, gb[j]);
    st[t] = min(m, N);
  }
  __syncthreads();
  for (int idx = t; idx < 1024; idx += 256) {
    int gi = idx >> 7, ch = idx & 127;
    float cnt = (float)(st[gi + 1] - st[gi]);
    g[gi][ch] = g_sum[idx] / fmaxf(cnt, 1.f);
  }
  __syncthreads();
  for (int idx = t; idx < 1024; idx += 256) {
    int gi = idx >> 7, j = idx & 127;
    float a = b1[j];
    for (int k = 0; k < 128; ++k) a += g[gi][k] * W1[(size_t)k * 128 + j];
    t1[gi][j] = fmaxf(a, 0.f);
  }
  __syncthreads();
  if (t < 8) {
    float a = b2[0];
    for (int j = 0; j < 128; ++j) a += t1[t][j] * W2[j];
    out[t] = a;
  }
}

// ---------------------------------------------------------------------------
extern "C" void kernel_launch(void* const* d_in, const int* in_sizes, int n_in,
                              void* d_out, int out_size, void* d_ws, size_t ws_size,
                              hipStream_t stream) {
  const float* x         = (const float*)d_in[0];
  const int*   edge_idx  = (const int*)d_in[1];
  const float* edge_attr = (const float*)d_in[2];
  const int*   batch     = (const int*)d_in[3];
  const float* recipe    = (const float*)d_in[4];
  const float* W_in      = (const float*)d_in[5];
  const float* b_in      = (const float*)d_in[6];
  const float* W_edge    = (const float*)d_in[7];
  const float* b_edge    = (const float*)d_in[8];
  const float* lin_w     = (const float*)d_in[9];
  const float* lin_edge_w= (const float*)d_in[10];
  const float* att_src   = (const float*)d_in[11];
  const float* att_dst   = (const float*)d_in[12];
  const float* att_edge  = (const float*)d_in[13];
  const float* gat_bias  = (const float*)d_in[14];
  const float* W1        = (const float*)d_in[15];
  const float* b1        = (const float*)d_in[16];
  const float* W2        = (const float*)d_in[17];
  const float* b2p       = (const float*)d_in[18];

  const int N = in_sizes[3];
  const int E = in_sizes[1] / 2;
  const int* src = edge_idx;
  const int* dst = edge_idx + E;

  // workspace layout (256B aligned slices)
  char* ws = (char*)d_ws;
  size_t off = 0;
  auto alloc = [&](size_t bytes) -> void* {
    void* p = ws + off;
    off += (bytes + 255) & ~(size_t)255;
    return p;
  };
  float* hA         = (float*)alloc((size_t)N * 128 * 4);
  float* hB         = (float*)alloc((size_t)N * 128 * 4);
  unsigned short* xlb = (unsigned short*)alloc((size_t)N * 128 * 2);  // bf16
  float* a_srcA     = (float*)alloc((size_t)N * 4 * 4);
  float* a_dstA     = (float*)alloc((size_t)N * 4 * 4);
  unsigned short* a_edge_csr = (unsigned short*)alloc((size_t)3 * E * 4 * 2);  // [L][E][4] bf16
  int*   src_csr    = (int*)alloc((size_t)E * 4);
  int*   rank       = (int*)alloc((size_t)E * 4);
  int*   perm       = (int*)alloc((size_t)E * 4);
  int*   row_ptr    = (int*)alloc((size_t)(N + 1) * 4);
  int*   deg        = (int*)alloc((size_t)N * 16 * 4);   // spread: one 64B line/node
  int*   scan_tmp   = (int*)alloc((size_t)N * 4);
  int*   bsum       = (int*)alloc(64 * 4);
  float* Mc         = (float*)alloc(204 * 4);
  unsigned short* wt_hi = (unsigned short*)alloc((size_t)3 * 16384 * 2);
  unsigned short* wt_lo = (unsigned short*)alloc((size_t)3 * 16384 * 2);
  float* g_sum      = (float*)alloc(8 * 128 * 4);
  int*   gb         = (int*)alloc(9 * 4);
  (void)ws_size; (void)n_in; (void)out_size;

  const int eb = (E + 255) / 256;
  const int rowtiles = (N + 63) / 64;
  const int nb = (N + 1023) / 1024;

  hipMemsetAsync(deg, 0, (size_t)N * 16 * 4, stream);
  hipMemsetAsync(g_sum, 0, 8 * 128 * 4, stream);
  hipMemsetAsync(gb, 0x7f, 9 * 4, stream);

  rank_kernel<<<eb, 256, 0, stream>>>(dst, deg, rank, E);
  scanA_kernel<<<nb, 1024, 0, stream>>>(deg, batch, scan_tmp, bsum, gb, N);
  scanC_kernel<<<nb, 1024, 0, stream>>>(deg, scan_tmp, bsum, nb, row_ptr, N);
  perm_kernel<<<eb, 256, 0, stream>>>(dst, src, rank, row_ptr, perm, src_csr, E);
  prep_wp_kernel<<<25, 256, 0, stream>>>(lin_w, wt_hi, wt_lo,
                                         lin_edge_w, att_edge, W_edge, b_edge, Mc);
  edge_build_kernel<<<eb, 256, 0, stream>>>(perm, edge_attr, Mc, a_edge_csr, E);
  proj_kernel<<<rowtiles, 256, 0, stream>>>(x, recipe, batch, W_in, b_in, hA, N);

  float* hcur = hA;
  float* hnxt = hB;
  for (int l = 0; l < 3; ++l) {
    gemm_mfma_kernel<<<rowtiles, 256, 0, stream>>>(hcur,
                                                   wt_hi + (size_t)l * 16384,
                                                   wt_lo + (size_t)l * 16384,
                                                   att_src + (size_t)l * 128,
                                                   att_dst + (size_t)l * 128,
                                                   xlb, a_srcA, a_dstA, N);
    node_kernel<<<(N + 3) / 4, 256, 0, stream>>>(row_ptr, src_csr, a_srcA, a_dstA,
                                                 a_edge_csr + (size_t)l * E * 4, xlb,
                                                 gat_bias + (size_t)l * 128, hnxt, N);
    float* tmp = hcur; hcur = hnxt; hnxt = tmp;
  }

  pool_kernel<<<256, 256, 0, stream>>>(hcur, gb, g_sum, N);
  head_kernel<<<1, 256, 0, stream>>>(g_sum, gb, W1, b1, W2, b2p, (float*)d_out, N);
}

// Round 20
// 436.574 us; speedup vs baseline: 1.0212x; 1.0212x over previous
//
#include <hip/hip_runtime.h>
#include <math.h>

// ---------------------------------------------------------------------------
// QoRNet: 3-layer GAT + pool + MLP head, fp32 (bf16 messages, MFMA GEMM).
// Edge GEMMs collapsed to E x 16 x 12 (only a_edge = <el,att_edge> is used).
// CSR (counting sort by dst) -> one wave per node, single-pass aggregation.
// R2-R17: see journal. Highlights: max-free softmax (R5), bf16 messages (R5),
// MFMA GEMM w/ split-precision weights (R6/7), gather-based CSR build (R4/13),
// boundary-based pool (R16), deg spread (R17).
// R18: 2x unroll REGRESSED (VGPR 28->40, occupancy 64->49%: traded away the
//      TLP that hid gather latency).
// R19: revert unroll; add index-only prefetch (next src_csr loaded during
//      current edge's compute; +2 VGPR) -> breaks the 2-step dependent chain
//      without the register cost.
// ---------------------------------------------------------------------------

typedef __attribute__((ext_vector_type(8))) __bf16 bf16x8;
typedef __attribute__((ext_vector_type(4))) float f32x4;

union FragU {
  uint4 u;
  bf16x8 v;
};

union XU {
  uint4 u[2];
  __bf16 b[16];
};

__device__ __forceinline__ float lrelu(float x) { return x >= 0.f ? x : 0.2f * x; }

__device__ __forceinline__ unsigned pack_bf2(float a, float b) {
  unsigned ua = __float_as_uint(a), ub = __float_as_uint(b);
  ua += 0x7fffu + ((ua >> 16) & 1u);   // RNE
  ub += 0x7fffu + ((ub >> 16) & 1u);
  return (ua >> 16) | (ub & 0xffff0000u);
}
__device__ __forceinline__ unsigned short bf_of(float a) {
  unsigned ua = __float_as_uint(a);
  ua += 0x7fffu + ((ua >> 16) & 1u);
  return (unsigned short)(ua >> 16);
}
__device__ __forceinline__ float bf_lo(unsigned u) { return __uint_as_float(u << 16); }
__device__ __forceinline__ float bf_hi(unsigned u) { return __uint_as_float(u & 0xffff0000u); }

// ---------- CSR build ----------
// deg spread: deg[node*16] -> one 64B L2 line per node (atomic contention fix)
__global__ void rank_kernel(const int* __restrict__ dst, int* __restrict__ deg,
                            int* __restrict__ rank, int E) {
  int e = blockIdx.x * 256 + threadIdx.x;
  if (e < E) rank[e] = atomicAdd(&deg[(size_t)dst[e] * 16], 1);
}

// Phase A: per-block inclusive scan (strided deg) + block total + gb boundaries
__global__ __launch_bounds__(1024) void scanA_kernel(const int* __restrict__ deg,
                                                     const int* __restrict__ batch,
                                                     int* __restrict__ tmp,
                                                     int* __restrict__ bsum,
                                                     int* __restrict__ gb, int n) {
  __shared__ int wsum[16];
  int tid = threadIdx.x;
  int lane = tid & 63, wid = tid >> 6;
  int i = blockIdx.x * 1024 + tid;
  // group boundaries of sorted batch (fused gb_kernel)
  if (i == 0) gb[8] = n;
  if (i < n) {
    int b = batch[i];
    if (i == 0 || batch[i - 1] != b) gb[b] = i;
  }
  int v = (i < n) ? deg[(size_t)i * 16] : 0;
  int sv = v;
#pragma unroll
  for (int off = 1; off < 64; off <<= 1) {
    int t = __shfl_up(sv, off);
    if (lane >= off) sv += t;
  }
  if (lane == 63) wsum[wid] = sv;
  __syncthreads();
  if (wid == 0) {
    int wv = (lane < 16) ? wsum[lane] : 0;
#pragma unroll
    for (int off = 1; off < 16; off <<= 1) {
      int t = __shfl_up(wv, off);
      if (lane >= off) wv += t;
    }
    if (lane < 16) wsum[lane] = wv;
  }
  __syncthreads();
  int waveoff = (wid > 0) ? wsum[wid - 1] : 0;
  int incl = waveoff + sv;
  if (i < n) tmp[i] = incl;
  if (tid == 1023) bsum[blockIdx.x] = incl;
}

// Phase C (scanB fused): each block scans the <=64 block sums itself.
__global__ __launch_bounds__(1024) void scanC_kernel(const int* __restrict__ deg,
                                                     const int* __restrict__ tmp,
                                                     const int* __restrict__ bsum, int nb,
                                                     int* __restrict__ row_ptr, int n) {
  __shared__ int soff[2];
  int tid = threadIdx.x;
  if (tid < 64) {
    int v = (tid < nb) ? bsum[tid] : 0;
    int sv = v;
#pragma unroll
    for (int off = 1; off < 64; off <<= 1) {
      int t = __shfl_up(sv, off);
      if (tid >= off) sv += t;
    }
    if (tid == blockIdx.x) soff[0] = sv - v;  // exclusive offset for this block
    if (tid == 63) soff[1] = sv;              // grand total
  }
  __syncthreads();
  int i = blockIdx.x * 1024 + tid;
  if (i < n) row_ptr[i] = tmp[i] - deg[(size_t)i * 16] + soff[0];
  if (blockIdx.x == 0 && tid == 0) row_ptr[n] = soff[1];
}

// perm[pos] = e and src_csr[pos] = srcA[e]
__global__ void perm_kernel(const int* __restrict__ dst, const int* __restrict__ srcA,
                            const int* __restrict__ rank, const int* __restrict__ row_ptr,
                            int* __restrict__ perm, int* __restrict__ src_csr, int E) {
  int e = blockIdx.x * 256 + threadIdx.x;
  if (e < E) {
    int pos = row_ptr[dst[e]] + rank[e];
    perm[pos] = e;
    src_csr[pos] = srcA[e];
  }
}

// ---------- fused parameter prep: blocks 0-23 = weight split+transpose,
// block 24 = edge matrix M[16][12]+cvec ----------
__global__ __launch_bounds__(256) void prep_wp_kernel(const float* __restrict__ lin_w,
                                                      unsigned short* __restrict__ wt_hi,
                                                      unsigned short* __restrict__ wt_lo,
                                                      const float* __restrict__ lin_edge_w,
                                                      const float* __restrict__ att_edge,
                                                      const float* __restrict__ W_edge,
                                                      const float* __restrict__ b_edge,
                                                      float* __restrict__ Mc) {
  __shared__ float shmem[128 * 18];
  int t = threadIdx.x;
  if (blockIdx.x < 24) {
    float(*tile)[18] = (float(*)[18])shmem;
    int l = blockIdx.x >> 3;
    int n0 = (blockIdx.x & 7) * 16;
    const float* W = lin_w + (size_t)l * 16384;
    unsigned short* hi = wt_hi + (size_t)l * 16384;
    unsigned short* lo = wt_lo + (size_t)l * 16384;
    for (int idx = t; idx < 2048; idx += 256) {
      int k = idx >> 4, j = idx & 15;
      tile[k][j] = W[k * 128 + n0 + j];
    }
    __syncthreads();
    int r = t >> 4;
    int k0 = (t & 15) * 8;
    unsigned short hbuf[8], lbuf[8];
#pragma unroll
    for (int u = 0; u < 8; ++u) {
      float w = tile[k0 + u][r];
      unsigned short hb = bf_of(w);
      float hf = __uint_as_float((unsigned)hb << 16);
      hbuf[u] = hb;
      lbuf[u] = bf_of(w - hf);
    }
    size_t base = (size_t)(n0 + r) * 128 + k0;
    *(uint4*)(hi + base) = *(uint4*)hbuf;
    *(uint4*)(lo + base) = *(uint4*)lbuf;
  } else {
    float(*WE)[12] = (float(*)[12])shmem;
    for (int idx = t; idx < 128 * 12; idx += 256) {
      int k = idx / 12, j = idx - k * 12;
      int l = j >> 2, h = j & 3;
      float s = 0.f;
      for (int c = 0; c < 32; ++c)
        s += lin_edge_w[((size_t)l * 128 + k) * 128 + h * 32 + c] * att_edge[(l * 4 + h) * 32 + c];
      WE[k][j] = s;
    }
    __syncthreads();
    for (int idx = t; idx < 16 * 12; idx += 256) {
      int i = idx / 12, j = idx - i * 12;
      float s = 0.f;
      for (int k = 0; k < 128; ++k) s += W_edge[i * 128 + k] * WE[k][j];
      Mc[idx] = s;
    }
    if (t < 12) {
      float s = 0.f;
      for (int k = 0; k < 128; ++k) s += b_edge[k] * WE[k][t];
      Mc[192 + t] = s;
    }
  }
}

// ---------- CSR-ordered edge build: gather edge_attr, write bf16 planes ----------
__global__ void edge_build_kernel(const int* __restrict__ perm,
                                  const float* __restrict__ edge_attr,
                                  const float* __restrict__ Mc,
                                  unsigned short* __restrict__ a_edge_csr,  // [L][E][4] bf16
                                  int E) {
  __shared__ float M[16][12];
  __shared__ float cv[12];
  int t = threadIdx.x;
  if (t < 192) M[t / 12][t % 12] = Mc[t];
  if (t < 12) cv[t] = Mc[192 + t];
  __syncthreads();
  int i = blockIdx.x * 256 + t;
  if (i >= E) return;
  int e = perm[i];
  const float4* p = (const float4*)(edge_attr + (size_t)e * 16);  // one 64B line
  float4 v0 = p[0], v1 = p[1], v2 = p[2], v3 = p[3];
  float ea[16] = {v0.x, v0.y, v0.z, v0.w, v1.x, v1.y, v1.z, v1.w,
                  v2.x, v2.y, v2.z, v2.w, v3.x, v3.y, v3.z, v3.w};
  float a[12];
#pragma unroll
  for (int j = 0; j < 12; ++j) {
    float s = cv[j];
#pragma unroll
    for (int k = 0; k < 16; ++k) s += ea[k] * M[k][j];
    a[j] = s;
  }
#pragma unroll
  for (int l = 0; l < 3; ++l) {
    uint2 o;
    o.x = pack_bf2(a[l * 4 + 0], a[l * 4 + 1]);  // lo=h0, hi=h1
    o.y = pack_bf2(a[l * 4 + 2], a[l * 4 + 3]);  // lo=h2, hi=h3
    *(uint2*)(a_edge_csr + ((size_t)l * E + i) * 4) = o;
  }
}

// ---------- input projection: h = relu([x, recipe[batch]] @ W_in + b_in) ----------
__global__ __launch_bounds__(256) void proj_kernel(const float* __restrict__ x,
                                                   const float* __restrict__ recipe,
                                                   const int* __restrict__ batch,
                                                   const float* __restrict__ W_in,
                                                   const float* __restrict__ b_in,
                                                   float* __restrict__ h, int N) {
  __shared__ float Wc[72][128];
  __shared__ float Ac[64][72];
  int t = threadIdx.x;
  int tx = t & 31, ty = t >> 5;
  int row0 = blockIdx.x * 64;
  for (int idx = t; idx < 2304; idx += 256) {
    int k = idx >> 5, c4 = idx & 31;
    *(float4*)&Wc[k][c4 * 4] = *(const float4*)(W_in + (size_t)k * 128 + c4 * 4);
  }
  for (int idx = t; idx < 1024; idx += 256) {
    int r = idx >> 4, c4 = idx & 15;
    int row = row0 + r;
    float4 v = make_float4(0.f, 0.f, 0.f, 0.f);
    if (row < N) v = *(const float4*)(x + (size_t)row * 64 + c4 * 4);
    *(float4*)&Ac[r][c4 * 4] = v;
  }
  for (int idx = t; idx < 128; idx += 256) {
    int r = idx >> 1, c4 = idx & 1;
    int row = row0 + r;
    float4 v = make_float4(0.f, 0.f, 0.f, 0.f);
    if (row < N) v = *(const float4*)(recipe + (size_t)batch[row] * 8 + c4 * 4);
    *(float4*)&Ac[r][64 + c4 * 4] = v;
  }
  __syncthreads();
  float4 bias = *(const float4*)(b_in + tx * 4);
  float4 acc[8];
#pragma unroll
  for (int s = 0; s < 8; ++s) acc[s] = bias;
  for (int k4 = 0; k4 < 18; ++k4) {
    float4 w0 = *(float4*)&Wc[k4 * 4 + 0][tx * 4];
    float4 w1 = *(float4*)&Wc[k4 * 4 + 1][tx * 4];
    float4 w2 = *(float4*)&Wc[k4 * 4 + 2][tx * 4];
    float4 w3 = *(float4*)&Wc[k4 * 4 + 3][tx * 4];
#pragma unroll
    for (int s = 0; s < 8; ++s) {
      float4 av = *(float4*)&Ac[ty + 8 * s][k4 * 4];
      acc[s].x += av.x * w0.x + av.y * w1.x + av.z * w2.x + av.w * w3.x;
      acc[s].y += av.x * w0.y + av.y * w1.y + av.z * w2.y + av.w * w3.y;
      acc[s].z += av.x * w0.z + av.y * w1.z + av.z * w2.z + av.w * w3.z;
      acc[s].w += av.x * w0.w + av.y * w1.w + av.z * w2.w + av.w * w3.w;
    }
  }
#pragma unroll
  for (int s = 0; s < 8; ++s) {
    int row = row0 + ty + 8 * s;
    if (row < N) {
      float4 o = acc[s];
      o.x = fmaxf(o.x, 0.f); o.y = fmaxf(o.y, 0.f);
      o.z = fmaxf(o.z, 0.f); o.w = fmaxf(o.w, 0.f);
      *(float4*)(h + (size_t)row * 128 + tx * 4) = o;
    }
  }
}

// ---------- xl(bf16) = h @ (W_hi + W_lo) via MFMA + a_src/a_dst epilogue ----
__global__ __launch_bounds__(256) void gemm_mfma_kernel(
    const float* __restrict__ A, const unsigned short* __restrict__ wt_hi,
    const unsigned short* __restrict__ wt_lo,
    const float* __restrict__ att_s, const float* __restrict__ att_d,
    unsigned short* __restrict__ Cb, float* __restrict__ a_src,
    float* __restrict__ a_dst, int M) {
  int t = threadIdx.x;
  int lane = t & 63, w = t >> 6;
  int c = lane & 15, q = lane >> 4;
  int m0 = blockIdx.x * 64 + w * 16;
  int rowA = m0 + c;
  bool rowok = rowA < M;

  f32x4 acc[8];
#pragma unroll
  for (int n = 0; n < 8; ++n) acc[n] = 0.f;

#pragma unroll
  for (int kk = 0; kk < 128; kk += 32) {
    float4 fa0 = make_float4(0.f, 0.f, 0.f, 0.f), fa1 = fa0;
    if (rowok) {
      const float* ap = A + (size_t)rowA * 128 + kk + 8 * q;
      fa0 = *(const float4*)ap;
      fa1 = *(const float4*)(ap + 4);
    }
    FragU af;
    af.u.x = pack_bf2(fa0.x, fa0.y);
    af.u.y = pack_bf2(fa0.z, fa0.w);
    af.u.z = pack_bf2(fa1.x, fa1.y);
    af.u.w = pack_bf2(fa1.z, fa1.w);
    const unsigned short* bhp = wt_hi + (size_t)c * 128 + kk + 8 * q;
    const unsigned short* blp = wt_lo + (size_t)c * 128 + kk + 8 * q;
#pragma unroll
    for (int n = 0; n < 8; ++n) {
      FragU bh, bl;
      bh.u = *(const uint4*)(bhp + n * 2048);  // (n*16)*128 shorts
      bl.u = *(const uint4*)(blp + n * 2048);
      acc[n] = __builtin_amdgcn_mfma_f32_16x16x32_bf16(af.v, bh.v, acc[n], 0, 0, 0);
      acc[n] = __builtin_amdgcn_mfma_f32_16x16x32_bf16(af.v, bl.v, acc[n], 0, 0, 0);
    }
  }

  // epilogue: xl bf16 stores + a_src/a_dst reductions
  float asr[4][2], adr[4][2];
#pragma unroll
  for (int hh = 0; hh < 4; ++hh) {
    asr[hh][0] = att_s[32 * hh + c];
    asr[hh][1] = att_s[32 * hh + 16 + c];
    adr[hh][0] = att_d[32 * hh + c];
    adr[hh][1] = att_d[32 * hh + 16 + c];
  }
#pragma unroll
  for (int i = 0; i < 4; ++i) {
    int row = m0 + 4 * q + i;
    bool ok = row < M;
    if (ok) {
      size_t base = (size_t)row * 128;
#pragma unroll
      for (int n = 0; n < 8; ++n) Cb[base + n * 16 + c] = bf_of(acc[n][i]);
    }
#pragma unroll
    for (int hh = 0; hh < 4; ++hh) {
      float ps = acc[2 * hh][i] * asr[hh][0] + acc[2 * hh + 1][i] * asr[hh][1];
      float pd = acc[2 * hh][i] * adr[hh][0] + acc[2 * hh + 1][i] * adr[hh][1];
#pragma unroll
      for (int off = 1; off < 16; off <<= 1) {
        ps += __shfl_xor(ps, off);
        pd += __shfl_xor(pd, off);
      }
      if (ok && c == hh) {
        a_src[(size_t)row * 4 + hh] = ps;
        a_dst[(size_t)row * 4 + hh] = pd;
      }
    }
  }
}

// ---------- fused per-node max-free softmax aggregation (wave per node) ----------
// Simple loop (R17 body) + index-only prefetch: next src_csr loads during
// current edge's compute (+2 VGPR, occupancy preserved).
__global__ __launch_bounds__(256) void node_kernel(const int* __restrict__ row_ptr,
                                                   const int* __restrict__ src_csr,
                                                   const float* __restrict__ a_src,
                                                   const float* __restrict__ a_dst,
                                                   const unsigned short* __restrict__ aep,  // [E][4] bf16 plane
                                                   const unsigned short* __restrict__ xlb,
                                                   const float* __restrict__ bias,
                                                   float* __restrict__ h_out, int N) {
  int lane = threadIdx.x & 63;
  int g = lane >> 3;        // edge group 0..7
  int t = lane & 7;         // channel lane, 16 ch each
  int h = t >> 1;           // head 0..3
  int n = blockIdx.x * 4 + (threadIdx.x >> 6);
  if (n >= N) return;
  int s = row_ptr[n], e = row_ptr[n + 1];

  const float* bp = bias + t * 16;
  float* op = h_out + (size_t)n * 128 + t * 16;
  if (e <= s) {
    if (g == 0) {
#pragma unroll
      for (int q = 0; q < 4; ++q) {
        float4 b = *(const float4*)(bp + q * 4);
        float4 o = make_float4(fmaxf(b.x, 0.f), fmaxf(b.y, 0.f), fmaxf(b.z, 0.f), fmaxf(b.w, 0.f));
        *(float4*)(op + q * 4) = o;
      }
    }
    return;
  }

  float ad = a_dst[(size_t)n * 4 + h];  // wave-uniform per head
  const unsigned* aepu = (const unsigned*)aep;
  int hw = h >> 1;   // which 32-bit word of the 8B entry
  int hb = h & 1;    // lo/hi half

  float den = 0.f;
  float num[16];
#pragma unroll
  for (int c = 0; c < 16; ++c) num[c] = 0.f;

  int i = s + g;
  int sc = (i < e) ? src_csr[i] : 0;
  for (; i < e; i += 8) {
    int inext = i + 8;
    int sc_next = (inext < e) ? src_csr[inext] : 0;   // prefetch next index
    float as = a_src[(size_t)sc * 4 + h];
    unsigned uae = aepu[(size_t)i * 2 + hw];
    const uint4* xp = (const uint4*)(xlb + (size_t)sc * 128 + t * 16);
    XU xu;
    xu.u[0] = xp[0];
    xu.u[1] = xp[1];  // 16 bf16
    float ae = hb ? bf_hi(uae) : bf_lo(uae);
    float a = lrelu(as + ad + ae);
    float w = __expf(fminf(a, 80.f));
    den += w;
#pragma unroll
    for (int c = 0; c < 16; ++c) num[c] += w * (float)xu.b[c];
    sc = sc_next;
  }

#pragma unroll
  for (int off = 8; off < 64; off <<= 1) {
    den += __shfl_xor(den, off);
#pragma unroll
    for (int c = 0; c < 16; ++c) num[c] += __shfl_xor(num[c], off);
  }

  if (g == 0) {
    float rh = 1.f / den;
#pragma unroll
    for (int q = 0; q < 4; ++q) {
      float4 b = *(const float4*)(bp + q * 4);
      float4 o;
      o.x = fmaxf(num[q * 4 + 0] * rh + b.x, 0.f);
      o.y = fmaxf(num[q * 4 + 1] * rh + b.y, 0.f);
      o.z = fmaxf(num[q * 4 + 2] * rh + b.z, 0.f);
      o.w = fmaxf(num[q * 4 + 3] * rh + b.w, 0.f);
      *(float4*)(op + q * 4) = o;
    }
  }
}

// ---------- pooling (mean): 8 groups x 32 chunks, branch-free, LDS reduce ----
__global__ __launch_bounds__(256) void pool_kernel(const float* __restrict__ h,
                                                   const int* __restrict__ gb,
                                                   float* __restrict__ g_sum, int N) {
  __shared__ int st[9];
  __shared__ float red[8][132];
  int t = threadIdx.x;
  if (t < 9) {
    int m = 0x7fffffff;
    for (int j = t; j < 9; ++j) m = min(m, gb[j]);   // gb[8] = N; unset groups huge
    st[t] = min(m, N);
  }
  __syncthreads();
  int g = blockIdx.x >> 5;       // group 0..7
  int chunk = blockIdx.x & 31;   // chunk 0..31
  int gs = st[g], ge = st[g + 1];
  int rows = ge - gs;
  int c4 = t & 31, sub = t >> 5; // 8 row-subs x 32 float4-lanes
  float ax = 0.f, ay = 0.f, az = 0.f, aw = 0.f;
  if (rows > 0) {
    int clen = (rows + 31) >> 5;
    int cs = gs + chunk * clen;
    int ce = min(cs + clen, ge);
    for (int r = cs + sub; r < ce; r += 8) {
      float4 v = *(const float4*)(h + (size_t)r * 128 + c4 * 4);
      ax += v.x; ay += v.y; az += v.z; aw += v.w;
    }
  }
  red[sub][c4 * 4 + 0] = ax;
  red[sub][c4 * 4 + 1] = ay;
  red[sub][c4 * 4 + 2] = az;
  red[sub][c4 * 4 + 3] = aw;
  __syncthreads();
  if (t < 128 && rows > 0) {
    float s = 0.f;
#pragma unroll
    for (int u = 0; u < 8; ++u) s += red[u][t];
    atomicAdd(&g_sum[(size_t)g * 128 + t], s);
  }
}

// ---------- head: relu(g@W1+b1)@W2+b2 ; counts from gb ----------
__global__ void head_kernel(const float* __restrict__ g_sum, const int* __restrict__ gb,
                            const float* __restrict__ W1, const float* __restrict__ b1,
                            const float* __restrict__ W2, const float* __restrict__ b2,
                            float* __restrict__ out, int N) {
  __shared__ float g[8][128];
  __shared__ float t1[8][128];
  __shared__ int st[9];
  int t = threadIdx.x;  // 256
  if (t < 9) {
    int m = 0x7fffffff;
    for (int j = t; j < 9; ++j) m = min(m, gb[j]);
    st[t] = min(m, N);
  }
  __syncthreads();
  for (int idx = t; idx < 1024; idx += 256) {
    int gi = idx >> 7, ch = idx & 127;
    float cnt = (float)(st[gi + 1] - st[gi]);
    g[gi][ch] = g_sum[idx] / fmaxf(cnt, 1.f);
  }
  __syncthreads();
  for (int idx = t; idx < 1024; idx += 256) {
    int gi = idx >> 7, j = idx & 127;
    float a = b1[j];
    for (int k = 0; k < 128; ++k) a += g[gi][k] * W1[(size_t)k * 128 + j];
    t1[gi][j] = fmaxf(a, 0.f);
  }
  __syncthreads();
  if (t < 8) {
    float a = b2[0];
    for (int j = 0; j < 128; ++j) a += t1[t][j] * W2[j];
    out[t] = a;
  }
}

// ---------------------------------------------------------------------------
extern "C" void kernel_launch(void* const* d_in, const int* in_sizes, int n_in,
                              void* d_out, int out_size, void* d_ws, size_t ws_size,
                              hipStream_t stream) {
  const float* x         = (const float*)d_in[0];
  const int*   edge_idx  = (const int*)d_in[1];
  const float* edge_attr = (const float*)d_in[2];
  const int*   batch     = (const int*)d_in[3];
  const float* recipe    = (const float*)d_in[4];
  const float* W_in      = (const float*)d_in[5];
  const float* b_in      = (const float*)d_in[6];
  const float* W_edge    = (const float*)d_in[7];
  const float* b_edge    = (const float*)d_in[8];
  const float* lin_w     = (const float*)d_in[9];
  const float* lin_edge_w= (const float*)d_in[10];
  const float* att_src   = (const float*)d_in[11];
  const float* att_dst   = (const float*)d_in[12];
  const float* att_edge  = (const float*)d_in[13];
  const float* gat_bias  = (const float*)d_in[14];
  const float* W1        = (const float*)d_in[15];
  const float* b1        = (const float*)d_in[16];
  const float* W2        = (const float*)d_in[17];
  const float* b2p       = (const float*)d_in[18];

  const int N = in_sizes[3];
  const int E = in_sizes[1] / 2;
  const int* src = edge_idx;
  const int* dst = edge_idx + E;

  // workspace layout (256B aligned slices)
  char* ws = (char*)d_ws;
  size_t off = 0;
  auto alloc = [&](size_t bytes) -> void* {
    void* p = ws + off;
    off += (bytes + 255) & ~(size_t)255;
    return p;
  };
  float* hA         = (float*)alloc((size_t)N * 128 * 4);
  float* hB         = (float*)alloc((size_t)N * 128 * 4);
  unsigned short* xlb = (unsigned short*)alloc((size_t)N * 128 * 2);  // bf16
  float* a_srcA     = (float*)alloc((size_t)N * 4 * 4);
  float* a_dstA     = (float*)alloc((size_t)N * 4 * 4);
  unsigned short* a_edge_csr = (unsigned short*)alloc((size_t)3 * E * 4 * 2);  // [L][E][4] bf16
  int*   src_csr    = (int*)alloc((size_t)E * 4);
  int*   rank       = (int*)alloc((size_t)E * 4);
  int*   perm       = (int*)alloc((size_t)E * 4);
  int*   row_ptr    = (int*)alloc((size_t)(N + 1) * 4);
  int*   deg        = (int*)alloc((size_t)N * 16 * 4);   // spread: one 64B line/node
  int*   scan_tmp   = (int*)alloc((size_t)N * 4);
  int*   bsum       = (int*)alloc(64 * 4);
  float* Mc         = (float*)alloc(204 * 4);
  unsigned short* wt_hi = (unsigned short*)alloc((size_t)3 * 16384 * 2);
  unsigned short* wt_lo = (unsigned short*)alloc((size_t)3 * 16384 * 2);
  float* g_sum      = (float*)alloc(8 * 128 * 4);
  int*   gb         = (int*)alloc(9 * 4);
  (void)ws_size; (void)n_in; (void)out_size;

  const int eb = (E + 255) / 256;
  const int rowtiles = (N + 63) / 64;
  const int nb = (N + 1023) / 1024;

  hipMemsetAsync(deg, 0, (size_t)N * 16 * 4, stream);
  hipMemsetAsync(g_sum, 0, 8 * 128 * 4, stream);
  hipMemsetAsync(gb, 0x7f, 9 * 4, stream);

  rank_kernel<<<eb, 256, 0, stream>>>(dst, deg, rank, E);
  scanA_kernel<<<nb, 1024, 0, stream>>>(deg, batch, scan_tmp, bsum, gb, N);
  scanC_kernel<<<nb, 1024, 0, stream>>>(deg, scan_tmp, bsum, nb, row_ptr, N);
  perm_kernel<<<eb, 256, 0, stream>>>(dst, src, rank, row_ptr, perm, src_csr, E);
  prep_wp_kernel<<<25, 256, 0, stream>>>(lin_w, wt_hi, wt_lo,
                                         lin_edge_w, att_edge, W_edge, b_edge, Mc);
  edge_build_kernel<<<eb, 256, 0, stream>>>(perm, edge_attr, Mc, a_edge_csr, E);
  proj_kernel<<<rowtiles, 256, 0, stream>>>(x, recipe, batch, W_in, b_in, hA, N);

  float* hcur = hA;
  float* hnxt = hB;
  for (int l = 0; l < 3; ++l) {
    gemm_mfma_kernel<<<rowtiles, 256, 0, stream>>>(hcur,
                                                   wt_hi + (size_t)l * 16384,
                                                   wt_lo + (size_t)l * 16384,
                                                   att_src + (size_t)l * 128,
                                                   att_dst + (size_t)l * 128,
                                                   xlb, a_srcA, a_dstA, N);
    node_kernel<<<(N + 3) / 4, 256, 0, stream>>>(row_ptr, src_csr, a_srcA, a_dstA,
                                                 a_edge_csr + (size_t)l * E * 4, xlb,
                                                 gat_bias + (size_t)l * 128, hnxt, N);
    float* tmp = hcur; hcur = hnxt; hnxt = tmp;
  }

  pool_kernel<<<256, 256, 0, stream>>>(hcur, gb, g_sum, N);
  head_kernel<<<1, 256, 0, stream>>>(g_sum, gb, W1, b1, W2, b2p, (float*)d_out, N);
}